// Round 9
// baseline (313.846 us; speedup 1.0000x reference)
//
#include <hip/hip_runtime.h>
#include <math.h>

#define N_RES 8192
#define N_IN  128
#define BATCH 16
#define LEAK  0.9f

#define NBK   256      // buckets (row>>5), 32 rows each
#define CAP1B 28672    // per-bucket capacity (avg 26.6K, +12 sigma)
#define CHUNK 4096     // entries per block chunk
#define SB2   (CAP1B / CHUNK)   // 7 chunks per bucket

// ws layout (bytes):
//   srcT     @ 0      : [8320][16] f32 transposed state|x  (532,480)
//   bcur     @ 1 MiB  : int[256]
//   partials @ 2 MiB  : [NBK][SB2][32][16] f32             (3,670,016)
//   e1       @ 8 MiB  : uint2[NBK][CAP1B]                  (58,720,256)
#define OFF_SRCT 0
#define OFF_BCUR (1u << 20)
#define OFF_PART (2u << 20)
#define OFF_E1   (8u << 20)
#define REQ_A    ((size_t)OFF_E1 + (size_t)NBK * CAP1B * 8)   // ~64 MiB

// ---------------------------------------------------------------------------
// transpose + zero bcur (block 0) — drops the separate memsetAsync dispatch.
__global__ __launch_bounds__(256) void transpose_kernel(
    const float* __restrict__ state,  // [BATCH][N_RES]
    const float* __restrict__ x,      // [BATCH][N_IN]
    float* __restrict__ srcT,         // [8320][BATCH]
    int* __restrict__ bcur) {
  int tid = blockIdx.x * 256 + threadIdx.x;
  if (blockIdx.x == 0) bcur[threadIdx.x] = 0;   // NBK == 256
  if (tid < N_RES * BATCH) {
    int b = tid >> 13;
    int r = tid & (N_RES - 1);
    srcT[r * BATCH + b] = state[tid];
  }
  if (tid < N_IN * BATCH) {
    int b = tid >> 7;
    int c = tid & (N_IN - 1);
    srcT[(N_RES + c) * BATCH + b] = x[tid];
  }
}

// ---------------------------------------------------------------------------
// Pass 1 (fused res+in): bin by row>>5 into 256 buckets; LDS reorder ->
// coalesced bin writes; parallel wave-shuffle prefix scan.
__global__ __launch_bounds__(256) void pass1_bin(
    const float* __restrict__ vres, const int* __restrict__ rres,
    const int* __restrict__ cres, int nres, int nbres,
    const float* __restrict__ vin, const int* __restrict__ rin,
    const int* __restrict__ cin, int nin,
    uint2* __restrict__ e1,          // [NBK][CAP1B]
    int* __restrict__ bcur) {        // [NBK]
  const float* vals; const int* rows; const int* cols;
  int nnz, col_off, base;
  if (blockIdx.x < nbres) {
    vals = vres; rows = rres; cols = cres; nnz = nres; col_off = 0;
    base = blockIdx.x * CHUNK;
  } else {
    vals = vin; rows = rin; cols = cin; nnz = nin; col_off = N_RES;
    base = (blockIdx.x - nbres) * CHUNK;
  }

  __shared__ int hist[NBK];
  __shared__ int lbase[NBK];
  __shared__ int gbase[NBK];
  __shared__ int wsum[4];
  __shared__ uint2 stg[CHUNK];          // 32 KB
  __shared__ unsigned char binof[CHUNK];
  int tid = threadIdx.x;
  hist[tid] = 0;
  __syncthreads();

  int n = nnz - base;
  if (n > CHUNK) n = CHUNK;

  uint2 ent[16];
  int bb[16], lp[16];
#pragma unroll
  for (int e = 0; e < 16; ++e) {
    int i = e * 256 + tid;
    bb[e] = -1;
    if (i < n) {
      int r = rows[base + i];
      int c = cols[base + i] + col_off;
      float v = vals[base + i];
      bb[e] = r >> 5;
      ent[e] = make_uint2(__float_as_uint(v),
                          ((unsigned)(r & 31) << 14) | (unsigned)c);
      lp[e] = atomicAdd(&hist[bb[e]], 1);
    }
  }
  __syncthreads();
  int h = hist[tid];
  int v = h;
#pragma unroll
  for (int d = 1; d < 64; d <<= 1) {
    int t = __shfl_up(v, d);
    if ((tid & 63) >= d) v += t;
  }
  if ((tid & 63) == 63) wsum[tid >> 6] = v;
  __syncthreads();
  int off = 0;
#pragma unroll
  for (int w = 0; w < 4; ++w)
    if (w < (tid >> 6)) off += wsum[w];
  lbase[tid] = off + v - h;
  gbase[tid] = h ? atomicAdd(&bcur[tid], h) : 0;
  __syncthreads();
#pragma unroll
  for (int e = 0; e < 16; ++e) {
    if (bb[e] >= 0) {
      int p = lbase[bb[e]] + lp[e];
      stg[p] = ent[e];
      binof[p] = (unsigned char)bb[e];
    }
  }
  __syncthreads();
  for (int i = tid; i < n; i += 256) {
    int b = binof[i];
    int p = gbase[b] + (i - lbase[b]);
    if (p < CAP1B) e1[(size_t)b * CAP1B + p] = stg[i];
  }
}

// ---------------------------------------------------------------------------
// Pass 2 fused sort+accumulate — ATOMIC-FREE ranking:
//   per-thread private u16 hist[bin][thread] (16 KB, 2-way bank alias = free)
//   -> per-bin wave prefix scans over thread columns -> 32-bin scan
//   -> in-place rank draw (read; use; write+1). Then the R8 segmented
//   register accumulation (zero atomics).
__global__ __launch_bounds__(256) void pass2_accum(
    const uint2* __restrict__ e1,
    const int* __restrict__ bcur,
    const float* __restrict__ srcT,     // [8320][16]
    float* __restrict__ partials) {     // [NBK][SB2][32][16]
  int bucket = blockIdx.x / SB2;
  int ch = blockIdx.x - bucket * SB2;
  int tid = threadIdx.x;
  float* __restrict__ pb = partials + ((size_t)bucket * SB2 + ch) * 512;

  int cnt = bcur[bucket];
  if (cnt > CAP1B) cnt = CAP1B;
  int base = ch * CHUNK;
  if (base >= cnt) {                    // block-uniform early exit
    for (int i = tid; i < 512; i += 256) pb[i] = 0.0f;
    return;
  }
  int n = cnt - base;
  if (n > CHUNK) n = CHUNK;

  __shared__ unsigned short hist[32 * 256];  // [bin][thread], 16 KB
  __shared__ int tot[32];
  __shared__ int sbase[33];
  __shared__ uint2 stg[CHUNK];               // 32 KB

  // zero hist (4096 dwords)
  unsigned* h32 = (unsigned*)hist;
  for (int i = tid; i < 4096; i += 256) h32[i] = 0;
  __syncthreads();

  const uint2* __restrict__ src = e1 + (size_t)bucket * CAP1B + base;
  uint2 ent[16];
  int rr_[16];
#pragma unroll
  for (int e = 0; e < 16; ++e) {
    int i = e * 256 + tid;
    rr_[e] = -1;
    if (i < n) {
      ent[e] = src[i];
      rr_[e] = (int)(ent[e].y >> 14);        // local row 0..31
      hist[rr_[e] * 256 + tid]++;            // private: read+inc+write, no atomic
    }
  }
  __syncthreads();

  // Per-bin prefix over the 256 thread-columns: wave w handles bins w*8..w*8+7.
  {
    int lane = tid & 63, w = tid >> 6;
    for (int b = w * 8; b < w * 8 + 8; ++b) {
      uint2 p = ((const uint2*)(hist + b * 256))[lane];   // 4 u16 counts
      int c0 = (int)(p.x & 0xffffu), c1 = (int)(p.x >> 16);
      int c2 = (int)(p.y & 0xffffu), c3 = (int)(p.y >> 16);
      int s = c0 + c1 + c2 + c3;
      int vv = s;
#pragma unroll
      for (int d = 1; d < 64; d <<= 1) {
        int t = __shfl_up(vv, d);
        if (lane >= d) vv += t;
      }
      int excl = vv - s;
      unsigned q0 = (unsigned)excl;
      unsigned q1 = (unsigned)(excl + c0);
      unsigned q2 = (unsigned)(excl + c0 + c1);
      unsigned q3 = (unsigned)(excl + c0 + c1 + c2);
      ((uint2*)(hist + b * 256))[lane] =
          make_uint2(q0 | (q1 << 16), q2 | (q3 << 16));
      if (lane == 63) tot[b] = vv;           // bin total
    }
  }
  __syncthreads();
  if (tid < 64) {                            // 32-bin scan -> sbase[33]
    int hh = (tid < 32) ? tot[tid] : 0;
    int vv = hh;
#pragma unroll
    for (int d = 1; d < 32; d <<= 1) {
      int t = __shfl_up(vv, d);
      if ((tid & 63) >= d) vv += t;
    }
    if (tid < 32) sbase[tid] = vv - hh;
    if (tid == 31) sbase[32] = vv;
  }
  __syncthreads();

  // Rank draw (in-place increment) + scatter into row-grouped stg.
#pragma unroll
  for (int e = 0; e < 16; ++e) {
    if (rr_[e] >= 0) {
      int b = rr_[e];
      int wc = (int)hist[b * 256 + tid];
      hist[b * 256 + tid] = (unsigned short)(wc + 1);
      stg[sbase[b] + wc] = ent[e];
    }
  }
  __syncthreads();

  // Segmented register accumulation: wave w rows w*8..w*8+7; 4 quarters x 16
  // batch-lanes, 4 entries/step, broadcast ds_read, one 64B srcT line/quarter.
  int wave = tid >> 6, lane = tid & 63;
  int q = lane >> 4, lb = lane & 15;
  for (int rr = wave * 8; rr < wave * 8 + 8; ++rr) {
    int s0 = sbase[rr], s1 = sbase[rr + 1];
    float acc = 0.0f;
    for (int i = s0 + q; i < s1; i += 4) {
      uint2 ee = stg[i];
      float vv = __uint_as_float(ee.x);
      int c = (int)(ee.y & 16383u);
      acc += vv * srcT[c * 16 + lb];
    }
    acc += __shfl_xor(acc, 16);
    acc += __shfl_xor(acc, 32);
    if (lane < 16) pb[rr * 16 + lb] = acc;
  }
}

// ---------------------------------------------------------------------------
__global__ __launch_bounds__(256) void finalize_fused(
    const float* __restrict__ partials,  // [NBK][SB2][32][16]
    const float* __restrict__ state,     // [BATCH][N_RES]
    const float* __restrict__ res_bias,
    const float* __restrict__ in_bias,
    float* __restrict__ out) {           // [BATCH][N_RES]
  int tid = blockIdx.x * 256 + threadIdx.x;
  if (tid >= N_RES * BATCH) return;
  int b = tid >> 13;
  int r = tid & (N_RES - 1);
  int bucket = r >> 5, rr = r & 31;
  const float* __restrict__ p =
      partials + (size_t)bucket * SB2 * 512 + rr * 16 + b;
  float z = 0.0f;
#pragma unroll
  for (int ch = 0; ch < SB2; ++ch) z += p[ch * 512];
  z += res_bias[r] + in_bias[r];
  out[tid] = (1.0f - LEAK) * state[tid] + LEAK * erff(z);
}

// ---------------------------------------------------------------------------
// Fallback (small ws): atomic path, correct but slow.
__global__ __launch_bounds__(256) void spmm_atomic(
    const float* __restrict__ vals,
    const int* __restrict__ rows,
    const int* __restrict__ cols,
    const float* __restrict__ srcT, int col_off,
    float* __restrict__ zz, int nnz) {
  int i = blockIdx.x * blockDim.x + threadIdx.x;
  if (i >= nnz) return;
  float v = vals[i];
  int r = rows[i];
  int c = cols[i] + col_off;
  const float4* __restrict__ sp = (const float4*)(srcT + c * BATCH);
  float* zr = zz + r * BATCH;
#pragma unroll
  for (int qq = 0; qq < 4; ++qq) {
    float4 s = sp[qq];
    unsafeAtomicAdd(zr + qq * 4 + 0, v * s.x);
    unsafeAtomicAdd(zr + qq * 4 + 1, v * s.y);
    unsafeAtomicAdd(zr + qq * 4 + 2, v * s.z);
    unsafeAtomicAdd(zr + qq * 4 + 3, v * s.w);
  }
}

__global__ __launch_bounds__(256) void finalize_z(
    const float* __restrict__ z,        // [N_RES][16]
    const float* __restrict__ state,
    const float* __restrict__ res_bias,
    const float* __restrict__ in_bias,
    float* __restrict__ out) {
  int tid = blockIdx.x * 256 + threadIdx.x;
  if (tid >= BATCH * N_RES) return;
  int b = tid >> 13;
  int r = tid & (N_RES - 1);
  float zz = z[r * 16 + b] + res_bias[r] + in_bias[r];
  out[tid] = (1.0f - LEAK) * state[tid] + LEAK * erff(zz);
}

__global__ __launch_bounds__(256) void transpose_nb(
    const float* __restrict__ state, const float* __restrict__ x,
    float* __restrict__ srcT) {
  int tid = blockIdx.x * 256 + threadIdx.x;
  if (tid < N_RES * BATCH) {
    int b = tid >> 13;
    int r = tid & (N_RES - 1);
    srcT[r * BATCH + b] = state[tid];
  }
  if (tid < N_IN * BATCH) {
    int b = tid >> 7;
    int c = tid & (N_IN - 1);
    srcT[(N_RES + c) * BATCH + b] = x[tid];
  }
}

// ---------------------------------------------------------------------------
extern "C" void kernel_launch(void* const* d_in, const int* in_sizes, int n_in,
                              void* d_out, int out_size, void* d_ws, size_t ws_size,
                              hipStream_t stream) {
  const float* state    = (const float*)d_in[0];
  const float* x        = (const float*)d_in[1];
  const float* res_vals = (const float*)d_in[2];
  const int*   res_rows = (const int*)d_in[3];
  const int*   res_cols = (const int*)d_in[4];
  const float* res_bias = (const float*)d_in[5];
  const float* in_vals  = (const float*)d_in[6];
  const int*   in_rows  = (const int*)d_in[7];
  const int*   in_cols  = (const int*)d_in[8];
  const float* in_bias  = (const float*)d_in[9];

  const int res_nnz = in_sizes[2];
  const int in_nnz  = in_sizes[6];

  char* ws = (char*)d_ws;
  float* srcT = (float*)(ws + OFF_SRCT);
  float* out = (float*)d_out;

  if (ws_size >= REQ_A) {
    int* bcur = (int*)(ws + OFF_BCUR);
    float* partials = (float*)(ws + OFF_PART);
    uint2* e1 = (uint2*)(ws + OFF_E1);

    transpose_kernel<<<512, 256, 0, stream>>>(state, x, srcT, bcur);

    int nbres = (res_nnz + CHUNK - 1) / CHUNK;
    int nbin  = (in_nnz + CHUNK - 1) / CHUNK;
    pass1_bin<<<nbres + nbin, 256, 0, stream>>>(
        res_vals, res_rows, res_cols, res_nnz, nbres,
        in_vals, in_rows, in_cols, in_nnz, e1, bcur);

    pass2_accum<<<NBK * SB2, 256, 0, stream>>>(e1, bcur, srcT, partials);

    finalize_fused<<<512, 256, 0, stream>>>(
        partials, state, res_bias, in_bias, out);
  } else {
    float* z = (float*)(ws + OFF_PART);
    hipMemsetAsync(z, 0, N_RES * BATCH * sizeof(float), stream);
    transpose_nb<<<512, 256, 0, stream>>>(state, x, srcT);
    spmm_atomic<<<(res_nnz + 255) / 256, 256, 0, stream>>>(
        res_vals, res_rows, res_cols, srcT, 0, z, res_nnz);
    spmm_atomic<<<(in_nnz + 255) / 256, 256, 0, stream>>>(
        in_vals, in_rows, in_cols, srcT, N_RES, z, in_nnz);
    finalize_z<<<512, 256, 0, stream>>>(z, state, res_bias, in_bias, out);
  }
}

// Round 10
// 293.823 us; speedup vs baseline: 1.0681x; 1.0681x over previous
//
#include <hip/hip_runtime.h>
#include <math.h>

#define N_RES 8192
#define N_IN  128
#define BATCH 16
#define LEAK  0.9f

#define NBK   256      // buckets (row>>5), 32 rows each
#define CAP1B 28672    // per-bucket capacity (avg 26.6K, +12 sigma)
#define CHUNK 4096     // entries per block chunk
#define SB2   (CAP1B / CHUNK)   // 7 chunks per bucket

// ws layout (bytes):
//   srcT     @ 0      : [8320][16] f32 transposed state|x  (532,480)
//   bcur     @ 1 MiB  : int[256]
//   partials @ 2 MiB  : [NBK][SB2][32][16] f32             (3,670,016)
//   e1       @ 8 MiB  : uint2[NBK][CAP1B]                  (58,720,256)
#define OFF_SRCT 0
#define OFF_BCUR (1u << 20)
#define OFF_PART (2u << 20)
#define OFF_E1   (8u << 20)
#define REQ_A    ((size_t)OFF_E1 + (size_t)NBK * CAP1B * 8)   // ~64 MiB

// ---------------------------------------------------------------------------
// transpose + zero bcur (block 0) — no separate memset dispatch.
__global__ __launch_bounds__(256) void transpose_kernel(
    const float* __restrict__ state,  // [BATCH][N_RES]
    const float* __restrict__ x,      // [BATCH][N_IN]
    float* __restrict__ srcT,         // [8320][BATCH]
    int* __restrict__ bcur) {
  int tid = blockIdx.x * 256 + threadIdx.x;
  if (blockIdx.x == 0) bcur[threadIdx.x] = 0;   // NBK == 256
  if (tid < N_RES * BATCH) {
    int b = tid >> 13;
    int r = tid & (N_RES - 1);
    srcT[r * BATCH + b] = state[tid];
  }
  if (tid < N_IN * BATCH) {
    int b = tid >> 7;
    int c = tid & (N_IN - 1);
    srcT[(N_RES + c) * BATCH + b] = x[tid];
  }
}

// ---------------------------------------------------------------------------
// Pass 1 (fused res+in): bin by row>>5 into 256 buckets.
// Ranking via ballot-match (8 bit-ballots) + leader-only u16 column counter:
// ZERO per-entry LDS atomics. Per-wave columns -> race-free.
__global__ __launch_bounds__(256) void pass1_bin(
    const float* __restrict__ vres, const int* __restrict__ rres,
    const int* __restrict__ cres, int nres, int nbres,
    const float* __restrict__ vin, const int* __restrict__ rin,
    const int* __restrict__ cin, int nin,
    uint2* __restrict__ e1,          // [NBK][CAP1B]
    int* __restrict__ bcur) {        // [NBK]
  const float* vals; const int* rows; const int* cols;
  int nnz, col_off, base;
  if (blockIdx.x < nbres) {
    vals = vres; rows = rres; cols = cres; nnz = nres; col_off = 0;
    base = blockIdx.x * CHUNK;
  } else {
    vals = vin; rows = rin; cols = cin; nnz = nin; col_off = N_RES;
    base = (blockIdx.x - nbres) * CHUNK;
  }

  __shared__ uint2 stg[CHUNK];               // 32 KB
  __shared__ unsigned char binof[CHUNK];     // 4 KB
  __shared__ unsigned short cbase[4][NBK];   // 2 KB (counts, then scatter bases)
  __shared__ unsigned short lbase[NBK];      // 512 B (exclusive prefix, <=4096)
  __shared__ unsigned short gbase[NBK];      // 512 B (global base, < CAP1B)
  __shared__ int wsum[4];

  int tid = threadIdx.x;
  int wave = tid >> 6, lane = tid & 63;

  for (int i = tid; i < 512; i += 256) ((unsigned*)cbase)[i] = 0;
  __syncthreads();

  int n = nnz - base;
  if (n > CHUNK) n = CHUNK;

  uint2 ent[16];
  int bb[16], lpv[16];
#pragma unroll
  for (int e = 0; e < 16; ++e) {
    int i = e * 256 + tid;
    bool act = (i < n);
    int r = 0, c = 0; float v = 0.f;
    if (act) { r = rows[base + i]; c = cols[base + i] + col_off; v = vals[base + i]; }
    int b = r >> 5;
    bb[e] = act ? b : -1;
    ent[e] = make_uint2(__float_as_uint(v),
                        ((unsigned)(r & 31) << 14) | (unsigned)c);
    unsigned long long mask = __ballot(act);
#pragma unroll
    for (int bit = 0; bit < 8; ++bit) {
      unsigned long long bs = __ballot(act && ((b >> bit) & 1));
      mask &= ((b >> bit) & 1) ? bs : ~bs;
    }
    int rank = __popcll(mask & ((1ull << lane) - 1ull));
    int cnt = __popcll(mask);
    int leader = mask ? (int)__builtin_ctzll(mask) : 0;
    int old = 0;
    if (act && lane == leader) {
      old = (int)cbase[wave][b];
      cbase[wave][b] = (unsigned short)(old + cnt);
    }
    old = __shfl(old, leader);
    lpv[e] = old + rank;
  }
  __syncthreads();

  // Totals + per-wave exclusive prefix; thread tid owns bin tid.
  int c0 = cbase[0][tid], c1 = cbase[1][tid], c2 = cbase[2][tid], c3 = cbase[3][tid];
  int h = c0 + c1 + c2 + c3;
  int v = h;
#pragma unroll
  for (int d = 1; d < 64; d <<= 1) {
    int t = __shfl_up(v, d);
    if (lane >= d) v += t;
  }
  if (lane == 63) wsum[wave] = v;
  __syncthreads();
  int off = 0;
#pragma unroll
  for (int w = 0; w < 4; ++w)
    if (w < wave) off += wsum[w];
  int lb = off + v - h;                       // exclusive prefix over 256 bins
  lbase[tid] = (unsigned short)lb;
  gbase[tid] = (unsigned short)(h ? atomicAdd(&bcur[tid], h) : 0);
  cbase[0][tid] = (unsigned short)lb;
  cbase[1][tid] = (unsigned short)(lb + c0);
  cbase[2][tid] = (unsigned short)(lb + c0 + c1);
  cbase[3][tid] = (unsigned short)(lb + c0 + c1 + c2);
  __syncthreads();

#pragma unroll
  for (int e = 0; e < 16; ++e) {
    if (bb[e] >= 0) {
      int p = (int)cbase[wave][bb[e]] + lpv[e];
      stg[p] = ent[e];
      binof[p] = (unsigned char)bb[e];
    }
  }
  __syncthreads();
  for (int i = tid; i < n; i += 256) {
    int b = binof[i];
    int p = (int)gbase[b] + (i - (int)lbase[b]);
    if (p < CAP1B) e1[(size_t)b * CAP1B + p] = stg[i];
  }
}

// ---------------------------------------------------------------------------
// Pass 2 fused sort+accumulate. Ranking via ballot-match (5 bit-ballots) +
// leader-only u16 column counters (zero per-entry LDS atomics), then the
// R8 segmented register accumulation (zero atomics).
__global__ __launch_bounds__(256) void pass2_accum(
    const uint2* __restrict__ e1,
    const int* __restrict__ bcur,
    const float* __restrict__ srcT,     // [8320][16]
    float* __restrict__ partials) {     // [NBK][SB2][32][16]
  int bucket = blockIdx.x / SB2;
  int ch = blockIdx.x - bucket * SB2;
  int tid = threadIdx.x;
  float* __restrict__ pb = partials + ((size_t)bucket * SB2 + ch) * 512;

  int cnt = bcur[bucket];
  if (cnt > CAP1B) cnt = CAP1B;
  int base = ch * CHUNK;
  if (base >= cnt) {                    // block-uniform early exit
    for (int i = tid; i < 512; i += 256) pb[i] = 0.0f;
    return;
  }
  int n = cnt - base;
  if (n > CHUNK) n = CHUNK;

  __shared__ uint2 stg[CHUNK];             // 32 KB
  __shared__ unsigned short cb2[4][32];    // 256 B
  __shared__ int sbase[33];

  int wave = tid >> 6, lane = tid & 63;
  if (tid < 64) ((unsigned*)cb2)[tid] = 0;
  __syncthreads();

  const uint2* __restrict__ src = e1 + (size_t)bucket * CAP1B + base;
  uint2 ent[16];
  int rr_[16], lpv[16];
#pragma unroll
  for (int e = 0; e < 16; ++e) {
    int i = e * 256 + tid;
    bool act = (i < n);
    uint2 en = make_uint2(0u, 0u);
    if (act) en = src[i];
    ent[e] = en;
    int b = (int)(en.y >> 14);            // local row 0..31 (c < 16384)
    rr_[e] = act ? b : -1;
    unsigned long long mask = __ballot(act);
#pragma unroll
    for (int bit = 0; bit < 5; ++bit) {
      unsigned long long bs = __ballot(act && ((b >> bit) & 1));
      mask &= ((b >> bit) & 1) ? bs : ~bs;
    }
    int rank = __popcll(mask & ((1ull << lane) - 1ull));
    int cntg = __popcll(mask);
    int leader = mask ? (int)__builtin_ctzll(mask) : 0;
    int old = 0;
    if (act && lane == leader) {
      old = (int)cb2[wave][b];
      cb2[wave][b] = (unsigned short)(old + cntg);
    }
    old = __shfl(old, leader);
    lpv[e] = old + rank;
  }
  __syncthreads();

  if (tid < 64) {                           // one wave: totals + scans
    int c0 = 0, c1 = 0, c2 = 0, c3 = 0, h = 0;
    if (tid < 32) {
      c0 = cb2[0][tid]; c1 = cb2[1][tid]; c2 = cb2[2][tid]; c3 = cb2[3][tid];
      h = c0 + c1 + c2 + c3;
    }
    int v = h;
#pragma unroll
    for (int d = 1; d < 32; d <<= 1) {
      int t = __shfl_up(v, d);
      if (lane >= d) v += t;
    }
    if (tid < 32) {
      int sb = v - h;
      sbase[tid] = sb;
      cb2[0][tid] = (unsigned short)sb;
      cb2[1][tid] = (unsigned short)(sb + c0);
      cb2[2][tid] = (unsigned short)(sb + c0 + c1);
      cb2[3][tid] = (unsigned short)(sb + c0 + c1 + c2);
    }
    if (tid == 31) sbase[32] = v;
  }
  __syncthreads();

#pragma unroll
  for (int e = 0; e < 16; ++e)
    if (rr_[e] >= 0) stg[(int)cb2[wave][rr_[e]] + lpv[e]] = ent[e];
  __syncthreads();

  // Segmented register accumulation: wave w rows w*8..w*8+7; 4 quarters x 16
  // batch-lanes, 4 entries/step, broadcast ds_read, one 64B srcT line/quarter.
  int q = lane >> 4, lbn = lane & 15;
  for (int rr = wave * 8; rr < wave * 8 + 8; ++rr) {
    int s0 = sbase[rr], s1 = sbase[rr + 1];
    float acc = 0.0f;
    for (int i = s0 + q; i < s1; i += 4) {
      uint2 ee = stg[i];
      float vv = __uint_as_float(ee.x);
      int c = (int)(ee.y & 16383u);
      acc += vv * srcT[c * 16 + lbn];
    }
    acc += __shfl_xor(acc, 16);
    acc += __shfl_xor(acc, 32);
    if (lane < 16) pb[rr * 16 + lbn] = acc;
  }
}

// ---------------------------------------------------------------------------
__global__ __launch_bounds__(256) void finalize_fused(
    const float* __restrict__ partials,  // [NBK][SB2][32][16]
    const float* __restrict__ state,     // [BATCH][N_RES]
    const float* __restrict__ res_bias,
    const float* __restrict__ in_bias,
    float* __restrict__ out) {           // [BATCH][N_RES]
  int tid = blockIdx.x * 256 + threadIdx.x;
  if (tid >= N_RES * BATCH) return;
  int b = tid >> 13;
  int r = tid & (N_RES - 1);
  int bucket = r >> 5, rr = r & 31;
  const float* __restrict__ p =
      partials + (size_t)bucket * SB2 * 512 + rr * 16 + b;
  float z = 0.0f;
#pragma unroll
  for (int ch = 0; ch < SB2; ++ch) z += p[ch * 512];
  z += res_bias[r] + in_bias[r];
  out[tid] = (1.0f - LEAK) * state[tid] + LEAK * erff(z);
}

// ---------------------------------------------------------------------------
// Fallback (small ws): atomic path, correct but slow.
__global__ __launch_bounds__(256) void spmm_atomic(
    const float* __restrict__ vals,
    const int* __restrict__ rows,
    const int* __restrict__ cols,
    const float* __restrict__ srcT, int col_off,
    float* __restrict__ zz, int nnz) {
  int i = blockIdx.x * blockDim.x + threadIdx.x;
  if (i >= nnz) return;
  float v = vals[i];
  int r = rows[i];
  int c = cols[i] + col_off;
  const float4* __restrict__ sp = (const float4*)(srcT + c * BATCH);
  float* zr = zz + r * BATCH;
#pragma unroll
  for (int qq = 0; qq < 4; ++qq) {
    float4 s = sp[qq];
    unsafeAtomicAdd(zr + qq * 4 + 0, v * s.x);
    unsafeAtomicAdd(zr + qq * 4 + 1, v * s.y);
    unsafeAtomicAdd(zr + qq * 4 + 2, v * s.z);
    unsafeAtomicAdd(zr + qq * 4 + 3, v * s.w);
  }
}

__global__ __launch_bounds__(256) void finalize_z(
    const float* __restrict__ z,        // [N_RES][16]
    const float* __restrict__ state,
    const float* __restrict__ res_bias,
    const float* __restrict__ in_bias,
    float* __restrict__ out) {
  int tid = blockIdx.x * 256 + threadIdx.x;
  if (tid >= BATCH * N_RES) return;
  int b = tid >> 13;
  int r = tid & (N_RES - 1);
  float zz = z[r * 16 + b] + res_bias[r] + in_bias[r];
  out[tid] = (1.0f - LEAK) * state[tid] + LEAK * erff(zz);
}

__global__ __launch_bounds__(256) void transpose_nb(
    const float* __restrict__ state, const float* __restrict__ x,
    float* __restrict__ srcT) {
  int tid = blockIdx.x * 256 + threadIdx.x;
  if (tid < N_RES * BATCH) {
    int b = tid >> 13;
    int r = tid & (N_RES - 1);
    srcT[r * BATCH + b] = state[tid];
  }
  if (tid < N_IN * BATCH) {
    int b = tid >> 7;
    int c = tid & (N_IN - 1);
    srcT[(N_RES + c) * BATCH + b] = x[tid];
  }
}

// ---------------------------------------------------------------------------
extern "C" void kernel_launch(void* const* d_in, const int* in_sizes, int n_in,
                              void* d_out, int out_size, void* d_ws, size_t ws_size,
                              hipStream_t stream) {
  const float* state    = (const float*)d_in[0];
  const float* x        = (const float*)d_in[1];
  const float* res_vals = (const float*)d_in[2];
  const int*   res_rows = (const int*)d_in[3];
  const int*   res_cols = (const int*)d_in[4];
  const float* res_bias = (const float*)d_in[5];
  const float* in_vals  = (const float*)d_in[6];
  const int*   in_rows  = (const int*)d_in[7];
  const int*   in_cols  = (const int*)d_in[8];
  const float* in_bias  = (const float*)d_in[9];

  const int res_nnz = in_sizes[2];
  const int in_nnz  = in_sizes[6];

  char* ws = (char*)d_ws;
  float* srcT = (float*)(ws + OFF_SRCT);
  float* out = (float*)d_out;

  if (ws_size >= REQ_A) {
    int* bcur = (int*)(ws + OFF_BCUR);
    float* partials = (float*)(ws + OFF_PART);
    uint2* e1 = (uint2*)(ws + OFF_E1);

    transpose_kernel<<<512, 256, 0, stream>>>(state, x, srcT, bcur);

    int nbres = (res_nnz + CHUNK - 1) / CHUNK;
    int nbin  = (in_nnz + CHUNK - 1) / CHUNK;
    pass1_bin<<<nbres + nbin, 256, 0, stream>>>(
        res_vals, res_rows, res_cols, res_nnz, nbres,
        in_vals, in_rows, in_cols, in_nnz, e1, bcur);

    pass2_accum<<<NBK * SB2, 256, 0, stream>>>(e1, bcur, srcT, partials);

    finalize_fused<<<512, 256, 0, stream>>>(
        partials, state, res_bias, in_bias, out);
  } else {
    float* z = (float*)(ws + OFF_PART);
    hipMemsetAsync(z, 0, N_RES * BATCH * sizeof(float), stream);
    transpose_nb<<<512, 256, 0, stream>>>(state, x, srcT);
    spmm_atomic<<<(res_nnz + 255) / 256, 256, 0, stream>>>(
        res_vals, res_rows, res_cols, srcT, 0, z, res_nnz);
    spmm_atomic<<<(in_nnz + 255) / 256, 256, 0, stream>>>(
        in_vals, in_rows, in_cols, srcT, N_RES, z, in_nnz);
    finalize_z<<<512, 256, 0, stream>>>(z, state, res_bias, in_bias, out);
  }
}